// Round 10
// baseline (273.155 us; speedup 1.0000x reference)
//
#include <hip/hip_runtime.h>

// Decoder: 2-layer LSTM (H=32) + MLP (96), B=16384, 25 steps.
// R10 = R9 barrier-free register recurrence + occupancy fix:
//  - ET=8 per wave -> 2048 single-wave blocks = 2 waves/SIMD (R9 had exactly
//    1/SIMD: 1024 waves on 1024 SIMDs, 85% exposed latency).
//  - bcomb/b1 biases hoisted to VGPRs (no per-step LDS reads at chain head).
//  - gates0 drops Wcomb.h1lo (error through sigmoid ~3e-4); hi/lo split kept
//    on the MLP output path only.
//  - pi(kq*8+j)=4j+kq K-permute keeps all handoffs lane-local (R9-proved).
//  - exp2-prescaled gates (R7-proved). Inputs/outputs f32 (R2-proved).

#define PRED 25
#define BATCH 16384

typedef unsigned short u16;
typedef unsigned int   u32;
typedef __attribute__((ext_vector_type(8))) short bf16x8;
typedef __attribute__((ext_vector_type(4))) float f32x4;

#define LOG2E  1.44269504088896340736f
#define LOG2E2 2.88539008177792681472f

__device__ __forceinline__ float rcp_(float x){ return __builtin_amdgcn_rcpf(x); }
__device__ __forceinline__ float ex2(float x){ return __builtin_amdgcn_exp2f(x); }
__device__ __forceinline__ float sigm2(float xp){ return rcp_(1.0f + ex2(-xp)); }
__device__ __forceinline__ float tanh2(float xp){ return 1.0f - 2.0f*rcp_(ex2(xp) + 1.0f); }

__device__ __forceinline__ u16 f2b(float f){
  u32 i = __float_as_uint(f);
  i += 0x7FFFu + ((i >> 16) & 1u);
  return (u16)(i >> 16);
}
__device__ __forceinline__ float b2f(u16 u){ return __uint_as_float(((u32)u) << 16); }

__device__ __forceinline__ float act_h(f32x4 g, float& c){
  float ig = sigm2(g[0]);
  float fg = sigm2(g[1]);
  float gg = tanh2(g[2]);
  float og = sigm2(g[3]);
  c = fmaf(fg, c, ig*gg);
  return og * tanh2(c*LOG2E2);
}

__device__ __forceinline__ bf16x8 packh(const float* h){
  union{bf16x8 v; u16 s[8];} r;
  #pragma unroll
  for (int j = 0; j < 8; ++j) r.s[j] = f2b(h[j]);
  return r.v;
}
__device__ __forceinline__ void pack_hilo(const float* h, bf16x8& hi, bf16x8& lo){
  union{bf16x8 v; u16 s[8];} H, L;
  #pragma unroll
  for (int j = 0; j < 8; ++j){
    u16 x = f2b(h[j]);
    H.s[j] = x;
    L.s[j] = f2b(h[j] - b2f(x));
  }
  hi = H.v; lo = L.v;
}

// ---------- prep: Wcomb[128][32] = Wih0 @ Wmlp ; bcomb[128] ----------
extern "C" __global__ void prep_kernel(const float* __restrict__ Wih0,
                                       const float* __restrict__ Wmlp,
                                       const float* __restrict__ bih0,
                                       const float* __restrict__ bhh0,
                                       const float* __restrict__ bmlp,
                                       float* __restrict__ ws){
  int idx = blockIdx.x*256 + threadIdx.x;
  if (idx < 4096){
    int g = idx >> 5, u = idx & 31;
    const float* wr = Wih0 + g*96;
    const float* wc = Wmlp + u;
    float a = 0.f;
    #pragma unroll 8
    for (int p = 0; p < 96; ++p) a = fmaf(wr[p], wc[p*32], a);
    ws[idx] = a;
  } else if (idx < 4224){
    int g = idx - 4096;
    const float* wr = Wih0 + g*96;
    float a = bih0[g] + bhh0[g];
    #pragma unroll 8
    for (int p = 0; p < 96; ++p) a = fmaf(wr[p], bmlp[p], a);
    ws[idx] = a;
  }
}

// ---------- main ----------
struct __align__(16) SM {
  float b00[128];    // t=0 gates0 bias, scaled (used once)
  float bm[96];      // MLP bias (natural)
  u16   wmf[6*64*8]; // Wm frags (pi-permuted), [im][lane][8]
};

extern "C" __global__ __launch_bounds__(64, 2)
void decoder_kernel(const float* __restrict__ obs,  const float* __restrict__ lat,
                    const float* __restrict__ Wfc,  const float* __restrict__ bfc,
                    const float* __restrict__ Wih0, const float* __restrict__ Whh0,
                    const float* __restrict__ bih0, const float* __restrict__ bhh0,
                    const float* __restrict__ Wih1, const float* __restrict__ Whh1,
                    const float* __restrict__ bih1, const float* __restrict__ bhh1,
                    const float* __restrict__ Wmlp, const float* __restrict__ bmlp,
                    const float* __restrict__ ws,   float* __restrict__ out)
{
  __shared__ SM sm;
  const int l  = threadIdx.x;
  const int lr = l & 15;      // frag row / e-column
  const int kq = l >> 4;      // k-quad
  const int el = lr & 7;      // clamped e (lanes 8-15 mirror 0-7)
  const int ebase = blockIdx.x * 8;

  // ---- stage t=0 bias + Wm frags + bm into LDS ----
  for (int v = l; v < 128; v += 64){
    int r = v & 3, u = v >> 2;
    int g = r*32 + u;
    float sc = (r == 2) ? LOG2E2 : LOG2E;
    sm.b00[v] = (bih0[g] + bhh0[g])*sc;
  }
  for (int v = l; v < 96; v += 64) sm.bm[v] = bmlp[v];
  #pragma unroll
  for (int im = 0; im < 6; ++im){
    int o = im*16 + lr;
    union{bf16x8 v; u16 s[8];} fr;
    #pragma unroll
    for (int j = 0; j < 8; ++j) fr.s[j] = f2b(Wmlp[o*32 + 4*j + kq]);
    *(bf16x8*)&sm.wmf[(im*64 + l)*8] = fr.v;
  }
  __syncthreads();

  // ---- persistent weight frags (pi-permuted K, gate-permuted M, scaled) ----
  bf16x8 wcombf[8], whh0f[8], wih1f[8], whh1f[8];
  #pragma unroll
  for (int i = 0; i < 8; ++i){
    int vg = i*16 + lr;
    int g  = (vg & 3)*32 + (vg >> 2);
    float sc = ((vg & 3) == 2) ? LOG2E2 : LOG2E;
    union{bf16x8 v; u16 s[8];} a, b, c, d;
    #pragma unroll
    for (int j = 0; j < 8; ++j){
      int col = 4*j + kq;               // pi(kq*8+j) = 4j+kq
      a.s[j] = f2b(ws[g*32 + col]*sc);          // Wcomb
      b.s[j] = f2b(Whh0[g*32 + col]*sc);
      c.s[j] = f2b(Wih1[g*32 + col]*sc);
      d.s[j] = f2b(Whh1[g*32 + col]*sc);
    }
    wcombf[i] = a.v; whh0f[i] = b.v; wih1f[i] = c.v; whh1f[i] = d.v;
  }
  // ---- biases in registers (no per-step LDS reads) ----
  f32x4 bcombr[8], b1r[8];
  #pragma unroll
  for (int i = 0; i < 8; ++i){
    int u = i*4 + kq;
    #pragma unroll
    for (int r = 0; r < 4; ++r){
      int g = r*32 + u;
      float sc = (r == 2) ? LOG2E2 : LOG2E;
      bcombr[i][r] = ws[4096 + g]*sc;
      b1r[i][r]    = (bih1[g] + bhh1[g])*sc;
    }
  }

  // ---- h_init = Wfc@latent + bfc, pi-packed (elem j = unit 4j+kq) ----
  float hinit[8];
  {
    const float* lp = lat + (size_t)(ebase + el)*16;
    float lv[16];
    #pragma unroll
    for (int j = 0; j < 16; ++j) lv[j] = lp[j];
    #pragma unroll
    for (int j = 0; j < 8; ++j){
      int u = 4*j + kq;
      const float* wf = Wfc + u*16;
      float a = bfc[u];
      #pragma unroll
      for (int p = 0; p < 16; ++p) a = fmaf(wf[p], lv[p], a);
      hinit[j] = a;
    }
  }
  bf16x8 h0f  = packh(hinit);
  bf16x8 h1hf = h0f;
  bf16x8 h1lof;
  { union{bf16x8 v; u16 s[8];} z;
    #pragma unroll
    for (int j = 0; j < 8; ++j) z.s[j] = 0;
    h1lof = z.v; }

  float c0a[8] = {0,0,0,0,0,0,0,0};
  float c1a[8] = {0,0,0,0,0,0,0,0};

  #pragma unroll 1
  for (int t = 0; t < PRED; ++t){
    float h0n[8];
    if (t == 0){
      // gates0(0) = Wih0 . x0 (natural K) + Whh0_pi . h_init + b00
      bf16x8 bx[3];
      const float* xr = obs + ((size_t)15*BATCH + ebase + el)*96;
      #pragma unroll
      for (int c = 0; c < 3; ++c){
        union{bf16x8 v; u16 s[8];} fr;
        const float* s8 = xr + c*32 + kq*8;
        #pragma unroll
        for (int j = 0; j < 8; ++j) fr.s[j] = f2b(s8[j]);
        bx[c] = fr.v;
      }
      #pragma unroll
      for (int i = 0; i < 8; ++i){
        int vg = i*16 + lr;
        int g  = (vg & 3)*32 + (vg >> 2);
        float sc = ((vg & 3) == 2) ? LOG2E2 : LOG2E;
        f32x4 acc = *(const f32x4*)&sm.b00[i*16 + kq*4];
        #pragma unroll
        for (int c = 0; c < 3; ++c){
          union{bf16x8 v; u16 s[8];} fr;
          const float* s8 = Wih0 + g*96 + c*32 + kq*8;
          #pragma unroll
          for (int j = 0; j < 8; ++j) fr.s[j] = f2b(s8[j]*sc);
          acc = __builtin_amdgcn_mfma_f32_16x16x32_bf16(fr.v, bx[c], acc, 0, 0, 0);
        }
        acc = __builtin_amdgcn_mfma_f32_16x16x32_bf16(whh0f[i], h0f, acc, 0, 0, 0);
        h0n[i] = act_h(acc, c0a[i]);
      }
    } else {
      // gates0(t) = Wcomb_pi.h1hi + Whh0_pi.h0 + bcomb   (h1lo dropped: ~3e-4)
      #pragma unroll
      for (int i = 0; i < 8; ++i){
        f32x4 acc = bcombr[i];
        acc = __builtin_amdgcn_mfma_f32_16x16x32_bf16(wcombf[i], h1hf, acc, 0, 0, 0);
        acc = __builtin_amdgcn_mfma_f32_16x16x32_bf16(whh0f[i],  h0f,  acc, 0, 0, 0);
        h0n[i] = act_h(acc, c0a[i]);
      }
    }
    bf16x8 h0nf = packh(h0n);
    // gates1 = Wih1_pi . h0_new + Whh1_pi . h1_prev + b1
    float h1n[8];
    #pragma unroll
    for (int i = 0; i < 8; ++i){
      f32x4 acc = b1r[i];
      acc = __builtin_amdgcn_mfma_f32_16x16x32_bf16(wih1f[i], h0nf, acc, 0, 0, 0);
      acc = __builtin_amdgcn_mfma_f32_16x16x32_bf16(whh1f[i], h1hf, acc, 0, 0, 0);
      h1n[i] = act_h(acc, c1a[i]);
    }
    h0f = h0nf;
    pack_hilo(h1n, h1hf, h1lof);   // after gates1 consumed h1_prev
    // MLP (off-chain): out[t] = Wm_pi.(h1hi+h1lo) + bm ; masked f32x4 stores
    float* ob = out + (size_t)t*BATCH*96 + (size_t)(ebase + lr)*96;
    #pragma unroll
    for (int im = 0; im < 6; ++im){
      bf16x8 wmv = *(const bf16x8*)&sm.wmf[(im*64 + l)*8];
      f32x4 acc = *(const f32x4*)&sm.bm[im*16 + kq*4];
      acc = __builtin_amdgcn_mfma_f32_16x16x32_bf16(wmv, h1hf,  acc, 0, 0, 0);
      acc = __builtin_amdgcn_mfma_f32_16x16x32_bf16(wmv, h1lof, acc, 0, 0, 0);
      if (lr < 8) *(f32x4*)(ob + im*16 + kq*4) = acc;
    }
  }
}

extern "C" void kernel_launch(void* const* d_in, const int* in_sizes, int n_in,
                              void* d_out, int out_size, void* d_ws, size_t ws_size,
                              hipStream_t stream){
  const float* obs  = (const float*)d_in[0];
  const float* lat  = (const float*)d_in[1];
  const float* Wfc  = (const float*)d_in[3];
  const float* bfc  = (const float*)d_in[4];
  const float* Wih0 = (const float*)d_in[5];
  const float* Whh0 = (const float*)d_in[6];
  const float* bih0 = (const float*)d_in[7];
  const float* bhh0 = (const float*)d_in[8];
  const float* Wih1 = (const float*)d_in[9];
  const float* Whh1 = (const float*)d_in[10];
  const float* bih1 = (const float*)d_in[11];
  const float* bhh1 = (const float*)d_in[12];
  const float* Wmlp = (const float*)d_in[13];
  const float* bmlp = (const float*)d_in[14];
  float* ws = (float*)d_ws;

  prep_kernel<<<dim3(17), dim3(256), 0, stream>>>(Wih0, Wmlp, bih0, bhh0, bmlp, ws);
  decoder_kernel<<<dim3(BATCH/8), dim3(64), 0, stream>>>(
      obs, lat, Wfc, bfc, Wih0, Whh0, bih0, bhh0,
      Wih1, Whh1, bih1, bhh1, Wmlp, bmlp, ws, (float*)d_out);
}

// Round 11
// 83.072 us; speedup vs baseline: 3.2882x; 3.2882x over previous
//
#include <hip/hip_runtime.h>

// Decoder: 2-layer LSTM (H=32) + MLP (96), B=16384, 25 steps.
// R11 = R8 shell (2-wave barrier'd m-split, dual-stream, 1 wave/SIMD) +
// R9/R10's Wcomb algebra: next x never materializes; per-step chain is
// GEMM1 -> B -> GEMM0 -> B (2 phases, 2 barriers), MLP+stores off-chain.
// pi(kq*8+j)=4j+kq K-permute keeps frags lane-local; LDS handoff is one
// ds_read_b128 / ds_write_b64 per stream. launch_bounds(128,1): no spill
// (R10 lesson: weights need >128 VGPR). Inputs/outputs f32 (R2-proved).

#define PRED 25
#define BATCH 16384
#define EST   48    // u16 stride per elem in LDS state bufs (16B-aligned, bank-spread)

typedef unsigned short u16;
typedef unsigned int   u32;
typedef __attribute__((ext_vector_type(8))) short bf16x8;
typedef __attribute__((ext_vector_type(4))) float f32x4;

#define LOG2E  1.44269504088896340736f
#define LOG2E2 2.88539008177792681472f

__device__ __forceinline__ float rcp_(float x){ return __builtin_amdgcn_rcpf(x); }
__device__ __forceinline__ float ex2(float x){ return __builtin_amdgcn_exp2f(x); }
__device__ __forceinline__ float sigm2(float xp){ return rcp_(1.0f + ex2(-xp)); }
__device__ __forceinline__ float tanh2(float xp){ return 1.0f - 2.0f*rcp_(ex2(xp) + 1.0f); }

__device__ __forceinline__ u16 f2b(float f){
  u32 i = __float_as_uint(f);
  i += 0x7FFFu + ((i >> 16) & 1u);
  return (u16)(i >> 16);
}
__device__ __forceinline__ float b2f(u16 u){ return __uint_as_float(((u32)u) << 16); }

__device__ __forceinline__ float act_h(f32x4 g, float& c){
  float ig = sigm2(g[0]);
  float fg = sigm2(g[1]);
  float gg = tanh2(g[2]);
  float og = sigm2(g[3]);
  c = fmaf(fg, c, ig*gg);
  return og * tanh2(c*LOG2E2);
}

// ---------- prep: ws[0..4095] = Wcomb[128][32] = Wih0 @ Wmlp ; ws[4096..4223] = bcomb ----------
extern "C" __global__ void prep_kernel(const float* __restrict__ Wih0,
                                       const float* __restrict__ Wmlp,
                                       const float* __restrict__ bih0,
                                       const float* __restrict__ bhh0,
                                       const float* __restrict__ bmlp,
                                       float* __restrict__ ws){
  int idx = blockIdx.x*256 + threadIdx.x;
  if (idx < 4096){
    int g = idx >> 5, u = idx & 31;
    const float* wr = Wih0 + g*96;
    const float* wc = Wmlp + u;
    float a = 0.f;
    #pragma unroll 8
    for (int p = 0; p < 96; ++p) a = fmaf(wr[p], wc[p*32], a);
    ws[idx] = a;
  } else if (idx < 4224){
    int g = idx - 4096;
    const float* wr = Wih0 + g*96;
    float a = bih0[g] + bhh0[g];
    #pragma unroll 8
    for (int p = 0; p < 96; ++p) a = fmaf(wr[p], bmlp[p], a);
    ws[idx] = a;
  }
}

// LDS state: pi-packed per-elem rows; m(u) = (u&3)*8 + (u>>2)
struct __align__(16) SM {
  u16 h0[32*EST];
  u16 h1h[32*EST];
  u16 h1lo[32*EST];
};

extern "C" __global__ __launch_bounds__(128, 1)
void decoder_kernel(const float* __restrict__ obs,  const float* __restrict__ lat,
                    const float* __restrict__ Wfc,  const float* __restrict__ bfc,
                    const float* __restrict__ Wih0, const float* __restrict__ Whh0,
                    const float* __restrict__ bih0, const float* __restrict__ bhh0,
                    const float* __restrict__ Wih1, const float* __restrict__ Whh1,
                    const float* __restrict__ bih1, const float* __restrict__ bhh1,
                    const float* __restrict__ Wmlp, const float* __restrict__ bmlp,
                    const float* __restrict__ ws,   float* __restrict__ out)
{
  __shared__ SM sm;
  const int tid = threadIdx.x;
  const int mh  = tid >> 6;       // wave = m-half
  const int l   = tid & 63;
  const int lr  = l & 15;         // frag row / e within stream
  const int kq  = l >> 4;         // k-quad
  const int ebase = blockIdx.x * 32;

  // ---- init: h_init -> h1h buffer (pi layout), zero h1lo ----
  for (int v = tid; v < 32*EST; v += 128) sm.h1lo[v] = 0;
  for (int v = tid; v < 1024; v += 128){
    int e = v >> 5, u = v & 31;
    const float* lp = lat + (size_t)(ebase + e)*16;
    const float* wf = Wfc + u*16;
    float a = bfc[u];
    #pragma unroll
    for (int p = 0; p < 16; ++p) a = fmaf(wf[p], lp[p], a);
    sm.h1h[e*EST + (u&3)*8 + (u>>2)] = f2b(a);
  }

  // ---- persistent weight frags (pi-K, gate-permuted M, exp2-prescaled) ----
  bf16x8 wcombf[4], whh0f[4], wih1f[4], whh1f[4];
  #pragma unroll
  for (int i = 0; i < 4; ++i){
    int vg = (mh*4 + i)*16 + lr;
    int g  = (vg & 3)*32 + (vg >> 2);
    float sc = ((vg & 3) == 2) ? LOG2E2 : LOG2E;
    union{bf16x8 v; u16 s[8];} a, b, c, d;
    #pragma unroll
    for (int j = 0; j < 8; ++j){
      int col = 4*j + kq;               // pi
      a.s[j] = f2b(ws[g*32 + col]*sc);
      b.s[j] = f2b(Whh0[g*32 + col]*sc);
      c.s[j] = f2b(Wih1[g*32 + col]*sc);
      d.s[j] = f2b(Whh1[g*32 + col]*sc);
    }
    wcombf[i] = a.v; whh0f[i] = b.v; wih1f[i] = c.v; whh1f[i] = d.v;
  }
  bf16x8 awm[3];                        // MLP A-frags (natural M, pi-K)
  #pragma unroll
  for (int im = 0; im < 3; ++im){
    int o = (mh*3 + im)*16 + lr;
    union{bf16x8 v; u16 s[8];} fr;
    #pragma unroll
    for (int j = 0; j < 8; ++j) fr.s[j] = f2b(Wmlp[o*32 + 4*j + kq]);
    awm[im] = fr.v;
  }
  // ---- register biases ----
  f32x4 bcombr[4], b1r[4];
  #pragma unroll
  for (int i = 0; i < 4; ++i){
    int u = (mh*4 + i)*4 + kq;
    #pragma unroll
    for (int r = 0; r < 4; ++r){
      int g = r*32 + u;
      float sc = (r == 2) ? LOG2E2 : LOG2E;
      bcombr[i][r] = ws[4096 + g]*sc;
      b1r[i][r]    = (bih1[g] + bhh1[g])*sc;
    }
  }
  f32x4 bmv[3];
  #pragma unroll
  for (int im = 0; im < 3; ++im){
    int o0 = (mh*3 + im)*16 + kq*4;
    #pragma unroll
    for (int r = 0; r < 4; ++r) bmv[im][r] = bmlp[o0 + r];
  }

  float c0a[2][4] = {{0,0,0,0},{0,0,0,0}};
  float c1a[2][4] = {{0,0,0,0},{0,0,0,0}};

  __syncthreads();   // h_init visible

  // ---- read h_init frags (serve as h0(-1) and h1(-1)) ----
  bf16x8 h1hfrag[2];
  #pragma unroll
  for (int s = 0; s < 2; ++s)
    h1hfrag[s] = *(const bf16x8*)&sm.h1h[(16*s + lr)*EST + kq*8];

  // ---- peel: GEMM0(0) = Wih0.x0 + Whh0.h_init + b00 -> h0(0) ----
  {
    bf16x8 bx[2][3];
    #pragma unroll
    for (int s = 0; s < 2; ++s){
      const float* xr = obs + ((size_t)15*BATCH + ebase + 16*s + lr)*96;
      #pragma unroll
      for (int c = 0; c < 3; ++c){
        union{bf16x8 v; u16 q[8];} fr;
        const float* s8 = xr + c*32 + kq*8;
        #pragma unroll
        for (int j = 0; j < 8; ++j) fr.q[j] = f2b(s8[j]);
        bx[s][c] = fr.v;
      }
    }
    #pragma unroll
    for (int i = 0; i < 4; ++i){
      int vg = (mh*4 + i)*16 + lr;
      int g  = (vg & 3)*32 + (vg >> 2);
      float sc = ((vg & 3) == 2) ? LOG2E2 : LOG2E;
      bf16x8 wf[3];
      #pragma unroll
      for (int c = 0; c < 3; ++c){
        union{bf16x8 v; u16 q[8];} fr;
        const float* s8 = Wih0 + g*96 + c*32 + kq*8;
        #pragma unroll
        for (int j = 0; j < 8; ++j) fr.q[j] = f2b(s8[j]*sc);
        wf[c] = fr.v;
      }
      int u = (mh*4 + i)*4 + kq;
      f32x4 b00;
      #pragma unroll
      for (int r = 0; r < 4; ++r){
        int gg = r*32 + u;
        b00[r] = (bih0[gg] + bhh0[gg])*((r == 2) ? LOG2E2 : LOG2E);
      }
      #pragma unroll
      for (int s = 0; s < 2; ++s){
        f32x4 acc = b00;
        acc = __builtin_amdgcn_mfma_f32_16x16x32_bf16(wf[0], bx[s][0], acc, 0, 0, 0);
        acc = __builtin_amdgcn_mfma_f32_16x16x32_bf16(wf[1], bx[s][1], acc, 0, 0, 0);
        acc = __builtin_amdgcn_mfma_f32_16x16x32_bf16(wf[2], bx[s][2], acc, 0, 0, 0);
        acc = __builtin_amdgcn_mfma_f32_16x16x32_bf16(whh0f[i], h1hfrag[s], acc, 0, 0, 0);
        float h = act_h(acc, c0a[s][i]);
        // write h0(0): unit u, elem 16s+lr -> m(u)=kq*8+mh*4+i (scalar u16)
        sm.h0[(16*s + lr)*EST + kq*8 + mh*4 + i] = f2b(h);
      }
    }
  }
  __syncthreads();   // h0(0) visible

  #pragma unroll 1
  for (int t = 0; t < PRED; ++t){
    // ---- read full h0(t) ----
    bf16x8 h0frag[2];
    #pragma unroll
    for (int s = 0; s < 2; ++s)
      h0frag[s] = *(const bf16x8*)&sm.h0[(16*s + lr)*EST + kq*8];
    // ---- GEMM1 + act1 -> h1(t) (hi to LDS; lo to LDS for MLP) ----
    #pragma unroll
    for (int s = 0; s < 2; ++s){
      union{u16 q[4]; u32 w[2];} hi4, lo4;
      #pragma unroll
      for (int i = 0; i < 4; ++i){
        f32x4 acc = b1r[i];
        acc = __builtin_amdgcn_mfma_f32_16x16x32_bf16(wih1f[i], h0frag[s], acc, 0, 0, 0);
        acc = __builtin_amdgcn_mfma_f32_16x16x32_bf16(whh1f[i], h1hfrag[s], acc, 0, 0, 0);
        float h = act_h(acc, c1a[s][i]);
        u16 hb = f2b(h);
        hi4.q[i] = hb;
        lo4.q[i] = f2b(h - b2f(hb));
      }
      int base = (16*s + lr)*EST + kq*8 + mh*4;
      *(u32*)&sm.h1h[base]      = hi4.w[0];
      *(u32*)&sm.h1h[base + 2]  = hi4.w[1];
      *(u32*)&sm.h1lo[base]     = lo4.w[0];
      *(u32*)&sm.h1lo[base + 2] = lo4.w[1];
    }
    __syncthreads();   // h1(t) visible
    // ---- read h1(t) frags ----
    bf16x8 h1lofrag[2];
    #pragma unroll
    for (int s = 0; s < 2; ++s){
      h1hfrag[s]  = *(const bf16x8*)&sm.h1h[(16*s + lr)*EST + kq*8];
      h1lofrag[s] = *(const bf16x8*)&sm.h1lo[(16*s + lr)*EST + kq*8];
    }
    // ---- GEMM0(t+1) (on-chain) ----
    if (t < PRED-1){
      #pragma unroll
      for (int s = 0; s < 2; ++s){
        union{u16 q[4]; u32 w[2];} h4;
        #pragma unroll
        for (int i = 0; i < 4; ++i){
          f32x4 acc = bcombr[i];
          acc = __builtin_amdgcn_mfma_f32_16x16x32_bf16(wcombf[i], h1hfrag[s], acc, 0, 0, 0);
          acc = __builtin_amdgcn_mfma_f32_16x16x32_bf16(whh0f[i],  h0frag[s],  acc, 0, 0, 0);
          float h = act_h(acc, c0a[s][i]);
          h4.q[i] = f2b(h);
        }
        int base = (16*s + lr)*EST + kq*8 + mh*4;
        *(u32*)&sm.h0[base]     = h4.w[0];
        *(u32*)&sm.h0[base + 2] = h4.w[1];
      }
    }
    // ---- MLP (off-chain) + stores ----
    #pragma unroll
    for (int s = 0; s < 2; ++s){
      float* ob = out + (size_t)t*BATCH*96 + (size_t)(ebase + 16*s + lr)*96;
      #pragma unroll
      for (int im = 0; im < 3; ++im){
        f32x4 acc = bmv[im];
        acc = __builtin_amdgcn_mfma_f32_16x16x32_bf16(awm[im], h1hfrag[s],  acc, 0, 0, 0);
        acc = __builtin_amdgcn_mfma_f32_16x16x32_bf16(awm[im], h1lofrag[s], acc, 0, 0, 0);
        *(f32x4*)(ob + (mh*3 + im)*16 + kq*4) = acc;
      }
    }
    if (t < PRED-1) __syncthreads();   // h0(t+1) visible
  }
}

extern "C" void kernel_launch(void* const* d_in, const int* in_sizes, int n_in,
                              void* d_out, int out_size, void* d_ws, size_t ws_size,
                              hipStream_t stream){
  const float* obs  = (const float*)d_in[0];
  const float* lat  = (const float*)d_in[1];
  const float* Wfc  = (const float*)d_in[3];
  const float* bfc  = (const float*)d_in[4];
  const float* Wih0 = (const float*)d_in[5];
  const float* Whh0 = (const float*)d_in[6];
  const float* bih0 = (const float*)d_in[7];
  const float* bhh0 = (const float*)d_in[8];
  const float* Wih1 = (const float*)d_in[9];
  const float* Whh1 = (const float*)d_in[10];
  const float* bih1 = (const float*)d_in[11];
  const float* bhh1 = (const float*)d_in[12];
  const float* Wmlp = (const float*)d_in[13];
  const float* bmlp = (const float*)d_in[14];
  float* ws = (float*)d_ws;

  prep_kernel<<<dim3(17), dim3(256), 0, stream>>>(Wih0, Wmlp, bih0, bhh0, bmlp, ws);
  decoder_kernel<<<dim3(BATCH/32), dim3(128), 0, stream>>>(
      obs, lat, Wfc, bfc, Wih0, Whh0, bih0, bhh0,
      Wih1, Whh1, bih1, bhh1, Wmlp, bmlp, ws, (float*)d_out);
}

// Round 12
// 79.096 us; speedup vs baseline: 3.4535x; 1.0503x over previous
//
#include <hip/hip_runtime.h>

// Decoder: 2-layer LSTM (H=32) + MLP (96), B=16384, 25 steps.
// R12 = R8 EXACTLY (best: 78.8us) with ONE change: in-loop __syncthreads()
// replaced by raw {s_waitcnt lgkmcnt(0); s_barrier} inline asm. This removes
// the compiler's s_waitcnt vmcnt(0) barrier drain, so per-step global stores
// (ack ~600-900cyc) stay in flight across barriers instead of landing on the
// critical path 3x per step. LDS correctness: lgkmcnt(0) commits ds_writes
// before each wave arrives. Inputs/outputs f32 (R2-proved).

#define PRED 25
#define BATCH 16384
#define ET    32    // 2 streams x 16
#define XROW  192   // xh row (u16): 0..95 x/curr, 96..127 h0_A, 128..159 h0_B
#define HROW  128   // hh row: 0..31 h0, 32..63 h1_A, 64..95 h1_B
#define LROW  64    // h1lo row

typedef unsigned short u16;
typedef unsigned int   u32;
typedef __attribute__((ext_vector_type(8))) short bf16x8;
typedef __attribute__((ext_vector_type(4))) float f32x4;

#define LOG2E  1.44269504088896340736f
#define LOG2E2 2.88539008177792681472f

// barrier WITHOUT vmcnt drain: waits only LDS ops, leaves global stores in flight
#define BARRIER_NOVM() asm volatile("s_waitcnt lgkmcnt(0)\ns_barrier" ::: "memory")

__device__ __forceinline__ float rcp_(float x){ return __builtin_amdgcn_rcpf(x); }
__device__ __forceinline__ float ex2(float x){ return __builtin_amdgcn_exp2f(x); }
// pre-acts pre-scaled: i/f/o rows by LOG2E, g rows by 2*LOG2E
__device__ __forceinline__ float sigm2(float xp){ return rcp_(1.0f + ex2(-xp)); }
__device__ __forceinline__ float tanh2(float xp){ return 1.0f - 2.0f*rcp_(ex2(xp) + 1.0f); }

__device__ __forceinline__ u16 f2b(float f){
  u32 i = __float_as_uint(f);
  i += 0x7FFFu + ((i >> 16) & 1u);
  return (u16)(i >> 16);
}
__device__ __forceinline__ float b2f(u16 u){ return __uint_as_float(((u32)u) << 16); }

struct __align__(16) SM {
  u16 xh[2][16*XROW];
  u16 hh[2][16*HROW];
  u16 h1lo[2][16*LROW];
};

__device__ __forceinline__ int swx(int e, int k){ return e*XROW + (k ^ ((e&7)<<3)); }
__device__ __forceinline__ int swh(int e, int k){ return e*HROW + (k ^ ((e&7)<<3)); }
__device__ __forceinline__ int swl(int e, int k){ return e*LROW + (k ^ ((e&7)<<3)); }

__device__ __forceinline__ bf16x8 pack8s(const float* src, float s){
  union { bf16x8 v; u16 h[8]; } fr;
  #pragma unroll
  for (int j = 0; j < 8; ++j) fr.h[j] = f2b(src[j]*s);
  return fr.v;
}

extern "C" __global__ __launch_bounds__(128, 1)
void decoder_kernel(const float* __restrict__ obs,  const float* __restrict__ lat,
                    const float* __restrict__ Wfc,  const float* __restrict__ bfc,
                    const float* __restrict__ Wih0, const float* __restrict__ Whh0,
                    const float* __restrict__ bih0, const float* __restrict__ bhh0,
                    const float* __restrict__ Wih1, const float* __restrict__ Whh1,
                    const float* __restrict__ bih1, const float* __restrict__ bhh1,
                    const float* __restrict__ Wmlp, const float* __restrict__ bmlp,
                    float* __restrict__ out)
{
  __shared__ SM sm;
  const int tid = threadIdx.x;
  const int ebase = blockIdx.x * ET;
  const int mh = tid >> 6;        // wave 0..1 = m-half
  const int l  = tid & 63;
  const int lr = l & 15;          // row/col in 16-tile; e within stream
  const int kq = l >> 4;          // k-quad 0..3

  // ---- one-time LDS init: x = obs[15] (bf16), h_init -> h0/h1 parity 0 ----
  {
    int e = tid >> 2, c0 = (tid & 3)*24;
    int s = e >> 4, er = e & 15;
    const float* src = obs + ((size_t)(15*BATCH) + ebase + e)*96 + c0;
    #pragma unroll
    for (int j = 0; j < 12; ++j){
      float2 v = *(const float2*)(src + 2*j);
      u32 pk = (u32)f2b(v.x) | ((u32)f2b(v.y) << 16);
      *(u32*)&sm.xh[s][swx(er, c0 + 2*j)] = pk;
    }
  }
  {
    int u = tid & 31, e8 = (tid >> 5)*8;
    const float* wf = Wfc + u*16;
    float bb = bfc[u];
    #pragma unroll
    for (int r = 0; r < 8; ++r){
      int e = e8 + r, s = e >> 4, er = e & 15;
      const float* lp = lat + (size_t)(ebase + e)*16;
      float a = bb;
      #pragma unroll
      for (int j = 0; j < 16; ++j) a = fmaf(wf[j], lp[j], a);
      u16 hb = f2b(a);
      sm.xh[s][swx(er, 96 + u)] = hb;   // h0 parity 0
      sm.hh[s][swh(er, 32 + u)] = hb;   // h1 parity 0
    }
  }

  // ---- preload weight A-fragments (step-invariant; gate rows pre-scaled) ----
  bf16x8 aw0[4][4];                 // GEMM0: 4 m-tiles x 4 k-chunks
  #pragma unroll
  for (int i = 0; i < 4; ++i){
    int vg = (mh*4 + i)*16 + lr;
    int g  = (vg & 3)*32 + (vg >> 2);     // gate-permuted row
    float sc = ((vg & 3) == 2) ? LOG2E2 : LOG2E;
    #pragma unroll
    for (int c = 0; c < 4; ++c){
      int k = c*32 + kq*8;
      const float* src = (k < 96) ? (Wih0 + g*96 + k) : (Whh0 + g*32 + (k - 96));
      aw0[i][c] = pack8s(src, sc);
    }
  }
  bf16x8 aw1[4][2];                 // GEMM1: K=64
  #pragma unroll
  for (int i = 0; i < 4; ++i){
    int vg = (mh*4 + i)*16 + lr;
    int g  = (vg & 3)*32 + (vg >> 2);
    float sc = ((vg & 3) == 2) ? LOG2E2 : LOG2E;
    #pragma unroll
    for (int c = 0; c < 2; ++c){
      int k = c*32 + kq*8;
      const float* src = (k < 32) ? (Wih1 + g*32 + k) : (Whh1 + g*32 + (k - 32));
      aw1[i][c] = pack8s(src, sc);
    }
  }
  bf16x8 awm[3];                    // MLP: 3 m-tiles per wave, K=32
  #pragma unroll
  for (int i = 0; i < 3; ++i){
    int o = (mh*3 + i)*16 + lr;
    awm[i] = pack8s(Wmlp + o*32 + kq*8, 1.0f);
  }

  // ---- biases (C-frag rows = kq*4 + r; scaled like their gate rows) ----
  f32x4 bias0v[4], bias1v[4];
  #pragma unroll
  for (int i = 0; i < 4; ++i){
    int u = (mh*4 + i)*4 + kq;
    #pragma unroll
    for (int r = 0; r < 4; ++r){
      int g = r*32 + u;
      float sc = (r == 2) ? LOG2E2 : LOG2E;
      bias0v[i][r] = (bih0[g] + bhh0[g])*sc;
      bias1v[i][r] = (bih1[g] + bhh1[g])*sc;
    }
  }
  f32x4 biasmv[3];
  #pragma unroll
  for (int i = 0; i < 3; ++i){
    int o0 = (mh*3 + i)*16 + kq*4;
    #pragma unroll
    for (int r = 0; r < 4; ++r) biasmv[i][r] = bmlp[o0 + r];
  }

  float c0s[2][4] = {{0,0,0,0},{0,0,0,0}};
  float c1s[2][4] = {{0,0,0,0},{0,0,0,0}};

  __syncthreads();   // init visible (one-time; full drain harmless here)

  f32x4 am[2][3];    // MLP results, stored to global AFTER B5

  for (int t = 0; t < PRED; ++t){
    const int p = t & 1;
    // ---- P1: GEMM0 both streams (independent -> ILP) ----
    f32x4 g0[2][4];
    #pragma unroll
    for (int s = 0; s < 2; ++s){
      bf16x8 bx0 = *(const bf16x8*)&sm.xh[s][swx(lr, 0*32 + kq*8)];
      bf16x8 bx1 = *(const bf16x8*)&sm.xh[s][swx(lr, 1*32 + kq*8)];
      bf16x8 bx2 = *(const bf16x8*)&sm.xh[s][swx(lr, 2*32 + kq*8)];
      bf16x8 bx3 = *(const bf16x8*)&sm.xh[s][swx(lr, 96 + 32*p + kq*8)];
      #pragma unroll
      for (int i = 0; i < 4; ++i){
        f32x4 a = bias0v[i];
        a = __builtin_amdgcn_mfma_f32_16x16x32_bf16(aw0[i][0], bx0, a, 0, 0, 0);
        a = __builtin_amdgcn_mfma_f32_16x16x32_bf16(aw0[i][1], bx1, a, 0, 0, 0);
        a = __builtin_amdgcn_mfma_f32_16x16x32_bf16(aw0[i][2], bx2, a, 0, 0, 0);
        a = __builtin_amdgcn_mfma_f32_16x16x32_bf16(aw0[i][3], bx3, a, 0, 0, 0);
        g0[s][i] = a;
      }
    }
    // ---- LSTM0 activation; h0 -> xh parity p^1 + hh rows 0..31 ----
    #pragma unroll
    for (int s = 0; s < 2; ++s)
      #pragma unroll
      for (int i = 0; i < 4; ++i){
        float ig = sigm2(g0[s][i][0]);
        float fg = sigm2(g0[s][i][1]);
        float gg = tanh2(g0[s][i][2]);
        float og = sigm2(g0[s][i][3]);
        float cn = fmaf(fg, c0s[s][i], ig*gg);
        c0s[s][i] = cn;
        u16 hb = f2b(og * tanh2(cn*LOG2E2));
        int u = (mh*4 + i)*4 + kq;
        sm.xh[s][swx(lr, 96 + 32*(p^1) + u)] = hb;
        sm.hh[s][swh(lr, u)] = hb;
      }
    BARRIER_NOVM();   // B2: h0 visible; stores stay in flight
    // ---- P3: GEMM1 both streams ----
    f32x4 g1[2][4];
    #pragma unroll
    for (int s = 0; s < 2; ++s){
      bf16x8 bh0 = *(const bf16x8*)&sm.hh[s][swh(lr, kq*8)];
      bf16x8 bh1 = *(const bf16x8*)&sm.hh[s][swh(lr, 32 + 32*p + kq*8)];
      #pragma unroll
      for (int i = 0; i < 4; ++i){
        f32x4 a = bias1v[i];
        a = __builtin_amdgcn_mfma_f32_16x16x32_bf16(aw1[i][0], bh0, a, 0, 0, 0);
        a = __builtin_amdgcn_mfma_f32_16x16x32_bf16(aw1[i][1], bh1, a, 0, 0, 0);
        g1[s][i] = a;
      }
    }
    #pragma unroll
    for (int s = 0; s < 2; ++s)
      #pragma unroll
      for (int i = 0; i < 4; ++i){
        float ig = sigm2(g1[s][i][0]);
        float fg = sigm2(g1[s][i][1]);
        float gg = tanh2(g1[s][i][2]);
        float og = sigm2(g1[s][i][3]);
        float cn = fmaf(fg, c1s[s][i], ig*gg);
        c1s[s][i] = cn;
        float h1 = og * tanh2(cn*LOG2E2);
        u16 hi = f2b(h1);
        u16 lo = f2b(h1 - b2f(hi));
        int u = (mh*4 + i)*4 + kq;
        sm.hh[s][swh(lr, 32 + 32*(p^1) + u)] = hi;   // h1_new
        sm.h1lo[s][swl(lr, u)] = lo;                 // residual for MLP split
      }
    BARRIER_NOVM();   // B4: h1 visible
    // ---- P4: MLP both streams; bf16 feedback to xh; f32 result deferred ----
    #pragma unroll
    for (int s = 0; s < 2; ++s){
      bf16x8 bmh = *(const bf16x8*)&sm.hh[s][swh(lr, 32 + 32*(p^1) + kq*8)];
      bf16x8 bml = *(const bf16x8*)&sm.h1lo[s][swl(lr, kq*8)];
      #pragma unroll
      for (int i = 0; i < 3; ++i){
        f32x4 a = biasmv[i];
        a = __builtin_amdgcn_mfma_f32_16x16x32_bf16(awm[i], bmh, a, 0, 0, 0);
        a = __builtin_amdgcn_mfma_f32_16x16x32_bf16(awm[i], bml, a, 0, 0, 0);
        am[s][i] = a;
        int o0 = (mh*3 + i)*16 + kq*4;
        u32 pk01 = (u32)f2b(a[0]) | ((u32)f2b(a[1]) << 16);
        u32 pk23 = (u32)f2b(a[2]) | ((u32)f2b(a[3]) << 16);
        *(u32*)&sm.xh[s][swx(lr, o0)]     = pk01;   // next step's x
        *(u32*)&sm.xh[s][swx(lr, o0 + 2)] = pk23;
      }
    }
    BARRIER_NOVM();   // B5: next x visible for P1(t+1)
    // ---- global stores AFTER barrier: never drained in-loop ----
    #pragma unroll
    for (int s = 0; s < 2; ++s){
      float* outb = out + (size_t)t*BATCH*96 + (size_t)(ebase + s*16 + lr)*96;
      #pragma unroll
      for (int i = 0; i < 3; ++i){
        int o0 = (mh*3 + i)*16 + kq*4;
        *(f32x4*)(outb + o0) = am[s][i];
      }
    }
  }
}

extern "C" void kernel_launch(void* const* d_in, const int* in_sizes, int n_in,
                              void* d_out, int out_size, void* d_ws, size_t ws_size,
                              hipStream_t stream){
  decoder_kernel<<<dim3(BATCH/ET), dim3(128), 0, stream>>>(
      (const float*)d_in[0],  (const float*)d_in[1],
      (const float*)d_in[3],  (const float*)d_in[4],
      (const float*)d_in[5],  (const float*)d_in[6],
      (const float*)d_in[7],  (const float*)d_in[8],
      (const float*)d_in[9],  (const float*)d_in[10],
      (const float*)d_in[11], (const float*)d_in[12],
      (const float*)d_in[13], (const float*)d_in[14],
      (float*)d_out);
}